// Round 15
// baseline (198.363 us; speedup 1.0000x reference)
//
#include <hip/hip_runtime.h>
#include <hip/hip_bf16.h>
#include <math.h>

#define BATCH 2
#define CH 512
#define SEQ 4096
#define KDIM 256
#define VDIM 512
#define NHEADS 8
#define DK 32
#define DV 64

typedef unsigned short u16;
typedef unsigned int u32;
typedef __attribute__((ext_vector_type(8))) short bf16x8;
typedef __attribute__((ext_vector_type(4))) float f32x4;

__device__ __forceinline__ u16 f2bf(float f) {          // RNE
    u32 x = __float_as_uint(f);
    u32 r = (x + 0x7fffu + ((x >> 16) & 1u)) >> 16;
    return (u16)r;
}
__device__ __forceinline__ u16 f2bf_fast(float f) {     // half-up
    return (u16)((__float_as_uint(f) + 0x8000u) >> 16);
}
__device__ __forceinline__ u32 pack2f(float lo, float hi) {
    return (u32)f2bf_fast(lo) | (((__float_as_uint(hi) + 0x8000u) >> 16) << 16);
}

#define QSCALE (0.17677669529663687f * 1.4426950408889634f)  // 1/sqrt(dk)*log2e

// ===========================================================================
// FAST PATH
// ===========================================================================

// prep: uniform 64x64 fp32->bf16 LDS transposes (validated rounds 11-14).
__global__ __launch_bounds__(256) void prep(
    const float* __restrict__ X,
    const float* __restrict__ Wq, const float* __restrict__ Wk,
    const float* __restrict__ Wv, const float* __restrict__ Wo,
    u16* __restrict__ Xb16, u16* __restrict__ Wall, u16* __restrict__ WoT)
{
    __shared__ u16 T[64 * 72];
    const int bid = blockIdx.x;
    const int t = threadIdx.x;
    const int tr = t >> 4;
    const int tc4 = (t & 15) * 4;

    const float* src; u16* dst;
    int src_row0, src_col0, src_pitch, dst_row0, dst_col0, dst_pitch;
    float scale = 1.0f;

    if (bid < 1024) {
        const int b = bid >> 9, rem = bid & 511;
        const int st = rem >> 3, ct = rem & 7;
        src = X + (size_t)b * CH * SEQ;
        src_row0 = ct * 64; src_col0 = st * 64; src_pitch = SEQ;
        dst = Xb16 + (size_t)b * SEQ * CH;
        dst_row0 = st * 64; dst_col0 = ct * 64; dst_pitch = CH;
    } else if (bid < 1152) {
        const int r = bid - 1024;
        const int nt = r >> 3, ct = r & 7;
        if (nt < 4)      { src = Wq; src_col0 = nt * 64;       src_pitch = KDIM; scale = QSCALE; }
        else if (nt < 8) { src = Wk; src_col0 = (nt - 4) * 64; src_pitch = KDIM; }
        else             { src = Wv; src_col0 = (nt - 8) * 64; src_pitch = VDIM; }
        src_row0 = ct * 64;
        dst = Wall; dst_row0 = nt * 64; dst_col0 = ct * 64; dst_pitch = 512;
    } else {
        const int r = bid - 1152;
        const int kt = r >> 3, nt = r & 7;
        src = Wo; src_row0 = kt * 64; src_col0 = nt * 64; src_pitch = 512;
        dst = WoT; dst_row0 = nt * 64; dst_col0 = kt * 64; dst_pitch = 512;
    }

#pragma unroll
    for (int j = 0; j < 4; ++j) {
        const int row = j * 16 + tr;
        const float4 v = *reinterpret_cast<const float4*>(
            &src[(size_t)(src_row0 + row) * src_pitch + src_col0 + tc4]);
        T[(tc4 + 0) * 72 + row] = f2bf(v.x * scale);
        T[(tc4 + 1) * 72 + row] = f2bf(v.y * scale);
        T[(tc4 + 2) * 72 + row] = f2bf(v.z * scale);
        T[(tc4 + 3) * 72 + row] = f2bf(v.w * scale);
    }
    __syncthreads();
#pragma unroll
    for (int j = 0; j < 4; ++j) {
        const int orow = j * 16 + tr;
        const ushort4 o = *reinterpret_cast<ushort4*>(&T[orow * 72 + tc4]);
        *reinterpret_cast<ushort4*>(
            &dst[(size_t)(dst_row0 + orow) * dst_pitch + dst_col0 + tc4]) = o;
    }
}

// ---------------------------------------------------------------------------
// qkv3: 128x128-tile GEMM over concatenated N=1024 (Q|K|V).
// waves_per_eu(2,4): LDS (40 KB) caps at 4 blocks/CU = 4 waves/EU, so the
// compiler must not throttle VGPRs toward a >4-waves/EU target (spill risk).
// ---------------------------------------------------------------------------
__global__ __launch_bounds__(256)
__attribute__((amdgpu_waves_per_eu(2, 4))) void qkv3(
    const u16* __restrict__ Xb16, const u16* __restrict__ Wall,
    u16* __restrict__ Qh, u16* __restrict__ Kh, u16* __restrict__ Vh)
{
    __shared__ __align__(16) u16 As[2][128 * 40];
    __shared__ __align__(16) u16 Bs[2][128 * 40];
    const int tid = threadIdx.x;
    const int wv = tid >> 6, lane = tid & 63;
    const int c = lane & 15, quad = lane >> 4;
    const int wm = wv & 1, wn = wv >> 1;
    const int m0 = blockIdx.x * 128;
    const int ny = blockIdx.y;           // 0..7 over concat N
    const int n0 = ny * 128;

    u16* Y; int N, nbase;
    if (ny < 2)      { Y = Qh; N = KDIM; nbase = 0; }
    else if (ny < 4) { Y = Kh; N = KDIM; nbase = 256; }
    else             { Y = Vh; N = VDIM; nbase = 512; }

    const int srow = tid >> 1, scol = (tid & 1) * 16;  // staging: row, 16-col

    f32x4 acc[4][4];
#pragma unroll
    for (int i = 0; i < 4; ++i)
#pragma unroll
        for (int g = 0; g < 4; ++g) acc[i][g] = (f32x4){0.f, 0.f, 0.f, 0.f};

    uint4 ar0, ar1, br0, br1;
    auto ld = [&](int k0) {
        const uint4* ap = reinterpret_cast<const uint4*>(
            &Xb16[(size_t)(m0 + srow) * 512 + k0 + scol]);
        ar0 = ap[0]; ar1 = ap[1];
        const uint4* bp = reinterpret_cast<const uint4*>(
            &Wall[(size_t)(n0 + srow) * 512 + k0 + scol]);
        br0 = bp[0]; br1 = bp[1];
    };
    auto stage = [&](int buf) {
        uint4* ad = reinterpret_cast<uint4*>(&As[buf][srow * 40 + scol]);
        ad[0] = ar0; ad[1] = ar1;
        uint4* bd = reinterpret_cast<uint4*>(&Bs[buf][srow * 40 + scol]);
        bd[0] = br0; bd[1] = br1;
    };

    ld(0);
    stage(0);
    ld(32);

    for (int i = 0; i < 16; ++i) {
        const int cur = i & 1;
        __syncthreads();
        stage(cur ^ 1);
        const int k0n = (i + 2 < 16) ? (i + 2) * 32 : 15 * 32;
        ld(k0n);
        bf16x8 af[4], bf_[4];
#pragma unroll
        for (int j = 0; j < 4; ++j) {
            af[j] = *reinterpret_cast<bf16x8*>(
                &As[cur][(wm * 64 + 16 * j + c) * 40 + quad * 8]);
            bf_[j] = *reinterpret_cast<bf16x8*>(
                &Bs[cur][(wn * 64 + 16 * j + c) * 40 + quad * 8]);
        }
#pragma unroll
        for (int j = 0; j < 4; ++j)
#pragma unroll
            for (int g = 0; g < 4; ++g)
                acc[j][g] = __builtin_amdgcn_mfma_f32_16x16x32_bf16(
                    af[j], bf_[g], acc[j][g], 0, 0, 0);
    }
#pragma unroll
    for (int j = 0; j < 4; ++j)
#pragma unroll
        for (int r = 0; r < 4; ++r) {
            const int row = m0 + wm * 64 + 16 * j + quad * 4 + r;
            const int col = n0 - nbase + wn * 64 + c;
#pragma unroll
            for (int g = 0; g < 4; ++g)
                Y[(size_t)row * N + col + 16 * g] = f2bf(acc[j][g][r]);
        }
}

// ---------------------------------------------------------------------------
// oproj3: 128x128-tile GEMM, same waves_per_eu treatment.
// ---------------------------------------------------------------------------
__global__ __launch_bounds__(256)
__attribute__((amdgpu_waves_per_eu(2, 4))) void oproj3(
    const u16* __restrict__ A, const u16* __restrict__ WoT,
    float* __restrict__ Out)
{
    __shared__ __align__(16) u16 As[2][128 * 40];
    __shared__ __align__(16) u16 Bs[2][128 * 40];
    const int tid = threadIdx.x;
    const int wv = tid >> 6, lane = tid & 63;
    const int c = lane & 15, quad = lane >> 4;
    const int wm = wv & 1, wn = wv >> 1;
    const int m0 = blockIdx.x * 128;
    const int n0 = blockIdx.y * 128;

    const int srow = tid >> 1, scol = (tid & 1) * 16;

    f32x4 acc[4][4];
#pragma unroll
    for (int i = 0; i < 4; ++i)
#pragma unroll
        for (int g = 0; g < 4; ++g) acc[i][g] = (f32x4){0.f, 0.f, 0.f, 0.f};

    uint4 ar0, ar1, br0, br1;
    auto ld = [&](int k0) {
        const uint4* ap = reinterpret_cast<const uint4*>(
            &A[(size_t)(m0 + srow) * 512 + k0 + scol]);
        ar0 = ap[0]; ar1 = ap[1];
        const uint4* bp = reinterpret_cast<const uint4*>(
            &WoT[(size_t)(n0 + srow) * 512 + k0 + scol]);
        br0 = bp[0]; br1 = bp[1];
    };
    auto stage = [&](int buf) {
        uint4* ad = reinterpret_cast<uint4*>(&As[buf][srow * 40 + scol]);
        ad[0] = ar0; ad[1] = ar1;
        uint4* bd = reinterpret_cast<uint4*>(&Bs[buf][srow * 40 + scol]);
        bd[0] = br0; bd[1] = br1;
    };

    ld(0);
    stage(0);
    ld(32);

    for (int i = 0; i < 16; ++i) {
        const int cur = i & 1;
        __syncthreads();
        stage(cur ^ 1);
        const int k0n = (i + 2 < 16) ? (i + 2) * 32 : 15 * 32;
        ld(k0n);
        bf16x8 af[4], bf_[4];
#pragma unroll
        for (int j = 0; j < 4; ++j) {
            af[j] = *reinterpret_cast<bf16x8*>(
                &As[cur][(wm * 64 + 16 * j + c) * 40 + quad * 8]);
            bf_[j] = *reinterpret_cast<bf16x8*>(
                &Bs[cur][(wn * 64 + 16 * j + c) * 40 + quad * 8]);
        }
#pragma unroll
        for (int j = 0; j < 4; ++j)
#pragma unroll
            for (int g = 0; g < 4; ++g)
                acc[j][g] = __builtin_amdgcn_mfma_f32_16x16x32_bf16(
                    af[j], bf_[g], acc[j][g], 0, 0, 0);
    }
#pragma unroll
    for (int j = 0; j < 4; ++j)
#pragma unroll
        for (int r = 0; r < 4; ++r) {
            const int row = m0 + wm * 64 + 16 * j + quad * 4 + r;
            const int col = n0 + wn * 64 + c;
#pragma unroll
            for (int g = 0; g < 4; ++g)
                Out[(size_t)row * 512 + col + 16 * g] = acc[j][g][r];
        }
}

// ===========================================================================
// flash v9 = v8 interleaved schedule + waves_per_eu(2,4).
// LDS (74 KB) caps at 2 blocks/CU = 4 waves/EU; the attribute stops the
// compiler from throttling VGPRs to 64 (an 8-waves/EU target LDS can never
// reach) — the sole cause of v8's spill (VGPR=64, WRITE_SIZE 25.6 MB).
// Schedule: QK_A, sm_A, writePA, QK_B, readPA, sm_B, writePB, PV_A,
// readPB, PV_B — each P write->read covered by independent work.
// ===========================================================================
__global__ __launch_bounds__(512)
__attribute__((amdgpu_waves_per_eu(2, 4))) void flash_mfma(
    const u16* __restrict__ Q, const u16* __restrict__ K,
    const u16* __restrict__ V, u16* __restrict__ AO)
{
    __shared__ __align__(16) union {
        struct {
            u16 Kl[2][2][64 * 40];
            u16 Vt[2][2][64 * 72];
            u16 Pl[8][16 * 72];
        } t;
        float mg[4][64][40];
    } sh;

    const int tid  = threadIdx.x;
    const int w    = tid >> 6;
    const int ws   = w & 3;
    const int wg   = w >> 2;
    const int lane = tid & 63;
    const int c    = lane & 15;
    const int quad = lane >> 4;
    const int h = blockIdx.y, b = blockIdx.z;

    const int qbA = blockIdx.x;
    const int qbB = 63 - qbA;
    const int q0A = qbA * 64, q0B = qbB * 64;

    const u16* Qb = Q + (size_t)b * SEQ * KDIM + h * DK;
    const u16* Kb = K + (size_t)b * SEQ * KDIM + h * DK;
    const u16* Vb = V + (size_t)b * SEQ * VDIM + h * DV;
    u16* AOb = AO + (size_t)b * SEQ * VDIM + h * DV;

    const bf16x8 qfA = *reinterpret_cast<const bf16x8*>(
        &Qb[(size_t)(q0A + ws * 16 + c) * KDIM + quad * 8]);
    const bf16x8 qfB = *reinterpret_cast<const bf16x8*>(
        &Qb[(size_t)(q0B + ws * 16 + c) * KDIM + quad * 8]);

    f32x4 oA[4], oB[4];
#pragma unroll
    for (int g = 0; g < 4; ++g) {
        oA[g] = (f32x4){0.f, 0.f, 0.f, 0.f};
        oB[g] = (f32x4){0.f, 0.f, 0.f, 0.f};
    }
    float lA[4] = {0.f, 0.f, 0.f, 0.f}, lB[4] = {0.f, 0.f, 0.f, 0.f};

    const int t256 = tid & 255;
    const int krow = t256 >> 2, kc8 = (t256 & 3) * 8;
    const int vs0 = (t256 & 31) * 2, vd0 = (t256 >> 5) * 8;

    u16* const Plw = sh.t.Pl[w];
    const int T = (qbB >> 1) + 1;

    uint4 kreg, vra, vrb;
    auto ldtile = [&](int kb) {
        const int k0 = kb * 64;
        kreg = *reinterpret_cast<const uint4*>(&Kb[(size_t)(k0 + krow) * KDIM + kc8]);
        vra  = *reinterpret_cast<const uint4*>(&Vb[(size_t)(k0 + vs0) * VDIM + vd0]);
        vrb  = *reinterpret_cast<const uint4*>(&Vb[(size_t)(k0 + vs0 + 1) * VDIM + vd0]);
    };
    auto stagetile = [&](int buf) {
        *reinterpret_cast<uint4*>(&sh.t.Kl[wg][buf][krow * 40 + kc8]) = kreg;
        union { uint4 q; u16 s[8]; } ra, rb;
        ra.q = vra; rb.q = vrb;
#pragma unroll
        for (int i = 0; i < 8; ++i) {
            u32 packed = (u32)ra.s[i] | ((u32)rb.s[i] << 16);
            *reinterpret_cast<u32*>(&sh.t.Vt[wg][buf][(vd0 + i) * 72 + vs0]) = packed;
        }
    };

    ldtile(wg);
    stagetile(0);
    ldtile(2 + wg);

    for (int it = 0; it < T; ++it) {
        const int kb = 2 * it + wg;
        const int k0 = kb * 64;
        const int cur = it & 1;
        __syncthreads();
        stagetile(cur ^ 1);
        {
            int kbn = 2 * (it + 2) + wg; if (kbn > 63) kbn = 63;
            ldtile(kbn);
        }
        const u16* Klc = sh.t.Kl[wg][cur];
        const u16* Vtc = sh.t.Vt[wg][cur];
        const bool actA = (kb <= qbA);
        const bool actB = (kb <= qbB);

        auto qk = [&](const bf16x8& qf, f32x4* s) {
#pragma unroll
            for (int g = 0; g < 4; ++g) {
                const bf16x8 kf = *reinterpret_cast<const bf16x8*>(
                    &Klc[(c + 16 * g) * 40 + quad * 8]);
                const f32x4 z = {0.f, 0.f, 0.f, 0.f};
                s[g] = __builtin_amdgcn_mfma_f32_16x16x32_bf16(qf, kf, z, 0, 0, 0);
            }
        };
        auto softmax_store = [&](f32x4* s, int q0, bool diag, float* l) {
            if (diag) {
#pragma unroll
                for (int g = 0; g < 4; ++g) {
                    const int kcol = k0 + c + 16 * g;
#pragma unroll
                    for (int r = 0; r < 4; ++r) {
                        const int qr = q0 + ws * 16 + quad * 4 + r;
                        if (kcol > qr) s[g][r] = -1e30f;
                    }
                }
            }
            float p[4][4];
            float rs[4] = {0.f, 0.f, 0.f, 0.f};
#pragma unroll
            for (int g = 0; g < 4; ++g)
#pragma unroll
                for (int r = 0; r < 4; ++r) {
                    const float e = __builtin_amdgcn_exp2f(s[g][r]);
                    p[g][r] = e;
                    rs[r] += e;
                }
#pragma unroll
            for (int off = 1; off < 16; off <<= 1)
#pragma unroll
                for (int r = 0; r < 4; ++r)
                    rs[r] += __shfl_xor(rs[r], off);
#pragma unroll
            for (int r = 0; r < 4; ++r) l[r] += rs[r];
#pragma unroll
            for (int g = 0; g < 4; ++g)
#pragma unroll
                for (int r = 0; r < 4; ++r)
                    Plw[(quad * 4 + r) * 72 + c + 16 * g] = f2bf_fast(p[g][r]);
        };
        auto pv = [&](const bf16x8& pa0, const bf16x8& pa1, f32x4* o) {
#pragma unroll
            for (int g = 0; g < 4; ++g) {
                const bf16x8 v0 = *reinterpret_cast<const bf16x8*>(
                    &Vtc[(c + 16 * g) * 72 + quad * 8]);
                const bf16x8 v1 = *reinterpret_cast<const bf16x8*>(
                    &Vtc[(c + 16 * g) * 72 + 32 + quad * 8]);
                o[g] = __builtin_amdgcn_mfma_f32_16x16x32_bf16(pa0, v0, o[g], 0, 0, 0);
                o[g] = __builtin_amdgcn_mfma_f32_16x16x32_bf16(pa1, v1, o[g], 0, 0, 0);
            }
        };

        f32x4 s[4];
        bf16x8 paA0, paA1, paB0, paB1;
        if (actA) {                       // QK_A + softmax_A + writePA
            qk(qfA, s);
            softmax_store(s, q0A, kb == qbA, lA);
        }
        if (actB) qk(qfB, s);             // QK_B (covers PA roundtrip)
        if (actA) {                       // readPA
            paA0 = *reinterpret_cast<bf16x8*>(&Plw[c * 72 + quad * 8]);
            paA1 = *reinterpret_cast<bf16x8*>(&Plw[c * 72 + 32 + quad * 8]);
        }
        if (actB)                         // softmax_B + writePB
            softmax_store(s, q0B, kb == qbB, lB);
        if (actA) pv(paA0, paA1, oA);     // PV_A (covers PB roundtrip)
        if (actB) {                       // readPB + PV_B
            paB0 = *reinterpret_cast<bf16x8*>(&Plw[c * 72 + quad * 8]);
            paB1 = *reinterpret_cast<bf16x8*>(&Plw[c * 72 + 32 + quad * 8]);
            pv(paB0, paB1, oB);
        }
    }

    __syncthreads();
    if (wg == 1) {
        float* m = sh.mg[ws][lane];
#pragma unroll
        for (int g = 0; g < 4; ++g)
#pragma unroll
            for (int r = 0; r < 4; ++r) {
                m[g * 4 + r]      = oA[g][r];
                m[16 + g * 4 + r] = oB[g][r];
            }
#pragma unroll
        for (int r = 0; r < 4; ++r) { m[32 + r] = lA[r]; m[36 + r] = lB[r]; }
    }
    __syncthreads();
    if (wg == 0) {
        const float* m = sh.mg[ws][lane];
#pragma unroll
        for (int g = 0; g < 4; ++g)
#pragma unroll
            for (int r = 0; r < 4; ++r) {
                oA[g][r] += m[g * 4 + r];
                oB[g][r] += m[16 + g * 4 + r];
            }
#pragma unroll
        for (int r = 0; r < 4; ++r) { lA[r] += m[32 + r]; lB[r] += m[36 + r]; }
#pragma unroll
        for (int r = 0; r < 4; ++r) {
            const float invA = 1.f / lA[r];
            const float invB = 1.f / lB[r];
            const int rowA = q0A + ws * 16 + quad * 4 + r;
            const int rowB = q0B + ws * 16 + quad * 4 + r;
#pragma unroll
            for (int g = 0; g < 4; ++g) {
                AOb[(size_t)rowA * VDIM + c + 16 * g] = f2bf(oA[g][r] * invA);
                AOb[(size_t)rowB * VDIM + c + 16 * g] = f2bf(oB[g][r] * invB);
            }
        }
    }
}

// ===========================================================================
// FALLBACK PATH (ws too small): round-10 projection kernels
// ===========================================================================
__global__ __launch_bounds__(256) void qkv_proj(
    const float* __restrict__ X,
    const float* __restrict__ Wq, const float* __restrict__ Wk,
    const float* __restrict__ Wv,
    u16* __restrict__ Qh, u16* __restrict__ Kh, u16* __restrict__ Vh)
{
    __shared__ __align__(16) u16 Xs[2][64 * 40];
    __shared__ __align__(16) u16 Wsm[2][64 * 40];
    const int tid = threadIdx.x;
    const int w = tid >> 6, lane = tid & 63;
    const int c = lane & 15, quad = lane >> 4;
    const int s0 = blockIdx.x * 64, b = blockIdx.z;
    const int ny = blockIdx.y;

    const float* Wt; u16* Y; int N, n0; float scale;
    if (ny < 4)       { Wt = Wq; Y = Qh; N = KDIM; n0 = ny * 64;       scale = QSCALE; }
    else if (ny < 8)  { Wt = Wk; Y = Kh; N = KDIM; n0 = (ny - 4) * 64; scale = 1.0f; }
    else              { Wt = Wv; Y = Vh; N = VDIM; n0 = (ny - 8) * 64; scale = 1.0f; }

    const float* Xb = X + (size_t)b * CH * SEQ;
    const int cp = tid >> 4;
    const int s4 = (tid & 15) * 4;

    f32x4 acc[4];
#pragma unroll
    for (int g = 0; g < 4; ++g) acc[g] = (f32x4){0.f, 0.f, 0.f, 0.f};

    auto ldx = [&](int c0, float4& a, float4& bb) {
        a  = *reinterpret_cast<const float4*>(&Xb[(size_t)(c0 + 2 * cp) * SEQ + s0 + s4]);
        bb = *reinterpret_cast<const float4*>(&Xb[(size_t)(c0 + 2 * cp + 1) * SEQ + s0 + s4]);
    };
    auto ldwf = [&](int c0, float4& a, float4& bb) {
        a  = *reinterpret_cast<const float4*>(&Wt[(size_t)(c0 + 2 * cp) * N + n0 + s4]);
        bb = *reinterpret_cast<const float4*>(&Wt[(size_t)(c0 + 2 * cp + 1) * N + n0 + s4]);
    };
    auto stage = [&](int buf, const float4& xa, const float4& xb,
                     const float4& wa, const float4& wb) {
        const float a[4] = {xa.x, xa.y, xa.z, xa.w};
        const float bb[4] = {xb.x, xb.y, xb.z, xb.w};
        const float aw[4] = {wa.x, wa.y, wa.z, wa.w};
        const float bw[4] = {wb.x, wb.y, wb.z, wb.w};
#pragma unroll
        for (int i = 0; i < 4; ++i) {
            *reinterpret_cast<u32*>(&Xs[buf][(s4 + i) * 40 + 2 * cp]) = pack2f(a[i], bb[i]);
            *reinterpret_cast<u32*>(&Wsm[buf][(s4 + i) * 40 + 2 * cp]) = pack2f(aw[i], bw[i]);
        }
    };

    float4 xa, xb, wa, wb;
    ldx(0, xa, xb); ldwf(0, wa, wb);
    stage(0, xa, xb, wa, wb);
    ldx(32, xa, xb); ldwf(32, wa, wb);

    for (int i = 0; i < 16; ++i) {
        const int cur = i & 1;
        __syncthreads();
        stage(cur ^ 1, xa, xb, wa, wb);
        const int c0n = (i + 2 < 16) ? (i + 2) * 32 : 15 * 32;
        ldx(c0n, xa, xb); ldwf(c0n, wa, wb);
        const bf16x8 af = *reinterpret_cast<bf16x8*>(&Xs[cur][(w * 16 + c) * 40 + quad * 8]);
#pragma unroll
        for (int g = 0; g < 4; ++g) {
            bf16x8 bf_ = *reinterpret_cast<bf16x8*>(&Wsm[cur][(c + 16 * g) * 40 + quad * 8]);
            acc[g] = __builtin_amdgcn_mfma_f32_16x16x32_bf16(af, bf_, acc[g], 0, 0, 0);
        }
    }
    u16* Yb = Y + (size_t)b * SEQ * N;
#pragma unroll
    for (int r = 0; r < 4; ++r) {
        const int row = s0 + w * 16 + quad * 4 + r;
#pragma unroll
        for (int g = 0; g < 4; ++g)
            Yb[(size_t)row * N + n0 + c + 16 * g] = f2bf(acc[g][r] * scale);
    }
}

__global__ __launch_bounds__(256) void oproj_mfma(
    const u16* __restrict__ A, const float* __restrict__ Wo,
    float* __restrict__ Out)
{
    __shared__ __align__(16) u16 Ws[2][64 * 40];
    const int tid = threadIdx.x;
    const int w = tid >> 6, lane = tid & 63;
    const int c = lane & 15, quad = lane >> 4;
    const int m0 = blockIdx.x * 64, n0 = blockIdx.y * 64;
    const int kp = tid >> 4;
    const int n4 = (tid & 15) * 4;
    const u16* Arow = &A[(size_t)(m0 + w * 16 + c) * 512];

    f32x4 acc[4];
#pragma unroll
    for (int g = 0; g < 4; ++g) acc[g] = (f32x4){0.f, 0.f, 0.f, 0.f};

    auto ldwf = [&](int k0, float4& a, float4& bb) {
        a  = *reinterpret_cast<const float4*>(&Wo[(size_t)(k0 + 2 * kp) * 512 + n0 + n4]);
        bb = *reinterpret_cast<const float4*>(&Wo[(size_t)(k0 + 2 * kp + 1) * 512 + n0 + n4]);
    };
    auto stage = [&](int buf, const float4& wa, const float4& wb) {
        const float a[4] = {wa.x, wa.y, wa.z, wa.w};
        const float bb[4] = {wb.x, wb.y, wb.z, wb.w};
#pragma unroll
        for (int i = 0; i < 4; ++i)
            *reinterpret_cast<u32*>(&Ws[buf][(n4 + i) * 40 + 2 * kp]) = pack2f(a[i], bb[i]);
    };

    float4 wa, wb;
    ldwf(0, wa, wb);
    stage(0, wa, wb);
    ldwf(32, wa, wb);
    bf16x8 afc = *reinterpret_cast<const bf16x8*>(&Arow[quad * 8]);

    for (int i = 0; i < 16; ++i) {
        const int cur = i & 1;
        __syncthreads();
        stage(cur ^ 1, wa, wb);
        const int k0n = (i + 2 < 16) ? (i + 2) * 32 : 15 * 32;
        ldwf(k0n, wa, wb);
        const int k0a = (i + 1 < 16) ? (i + 1) * 32 : 15 * 32;
        const bf16x8 afn = *reinterpret_cast<const bf16x8*>(&Arow[k0a + quad * 8]);
#pragma unroll
        for (int g = 0; g < 4; ++g) {
            bf16x8 bf_ = *reinterpret_cast<bf16x8*>(&Ws[cur][(c + 16 * g) * 40 + quad * 8]);
            acc[g] = __builtin_amdgcn_mfma_f32_16x16x32_bf16(afc, bf_, acc[g], 0, 0, 0);
        }
        afc = afn;
    }
#pragma unroll
    for (int r = 0; r < 4; ++r) {
        const int row = m0 + w * 16 + quad * 4 + r;
#pragma unroll
        for (int g = 0; g < 4; ++g)
            Out[(size_t)row * 512 + n0 + c + 16 * g] = acc[g][r];
    }
}

extern "C" void kernel_launch(void* const* d_in, const int* in_sizes, int n_in,
                              void* d_out, int out_size, void* d_ws, size_t ws_size,
                              hipStream_t stream) {
    const float* X  = (const float*)d_in[0];
    const float* Wq = (const float*)d_in[1];
    const float* Wk = (const float*)d_in[2];
    const float* Wv = (const float*)d_in[3];
    const float* Wo = (const float*)d_in[4];
    float* out = (float*)d_out;

    const size_t qk = (size_t)BATCH * SEQ * KDIM;
    const size_t vs = (size_t)BATCH * SEQ * VDIM;
    u16* Qh  = (u16*)d_ws;        // 4 MB
    u16* Kh  = Qh + qk;           // 4 MB
    u16* Vh  = Kh + qk;           // 8 MB
    u16* XA  = Vh + vs;           // 8 MB: Xb16 during qkv, AOh after flash
    u16* Wall = XA + vs;          // 1 MB
    u16* WoT  = Wall + 1024 * 512;// 0.5 MB
    const size_t need_fast = (size_t)(WoT + 512 * 512 - (u16*)d_ws) * sizeof(u16);

    if (ws_size >= need_fast) {
        prep<<<dim3(1216), 256, 0, stream>>>(X, Wq, Wk, Wv, Wo, XA, Wall, WoT);
        qkv3<<<dim3((BATCH * SEQ) / 128, 8), 256, 0, stream>>>(XA, Wall, Qh, Kh, Vh);
        flash_mfma<<<dim3(32, NHEADS, BATCH), 512, 0, stream>>>(Qh, Kh, Vh, XA);
        oproj3<<<dim3((BATCH * SEQ) / 128, 4), 256, 0, stream>>>(XA, WoT, out);
    } else {
        u16* AOh = XA;
        qkv_proj<<<dim3(SEQ / 64, 16, BATCH), 256, 0, stream>>>(
            X, Wq, Wk, Wv, Qh, Kh, Vh);
        flash_mfma<<<dim3(32, NHEADS, BATCH), 512, 0, stream>>>(Qh, Kh, Vh, AOh);
        oproj_mfma<<<dim3((BATCH * SEQ) / 64, VDIM / 64), 256, 0, stream>>>(AOh, Wo, out);
    }
}

// Round 16
// 159.443 us; speedup vs baseline: 1.2441x; 1.2441x over previous
//
#include <hip/hip_runtime.h>
#include <hip/hip_bf16.h>
#include <math.h>

#define BATCH 2
#define CH 512
#define SEQ 4096
#define KDIM 256
#define VDIM 512
#define NHEADS 8
#define DK 32
#define DV 64

typedef unsigned short u16;
typedef unsigned int u32;
typedef __attribute__((ext_vector_type(8))) short bf16x8;
typedef __attribute__((ext_vector_type(4))) float f32x4;

__device__ __forceinline__ u16 f2bf(float f) {          // RNE
    u32 x = __float_as_uint(f);
    u32 r = (x + 0x7fffu + ((x >> 16) & 1u)) >> 16;
    return (u16)r;
}
__device__ __forceinline__ u16 f2bf_fast(float f) {     // half-up
    return (u16)((__float_as_uint(f) + 0x8000u) >> 16);
}
__device__ __forceinline__ u32 pack2f(float lo, float hi) {
    return (u32)f2bf_fast(lo) | (((__float_as_uint(hi) + 0x8000u) >> 16) << 16);
}

#define QSCALE (0.17677669529663687f * 1.4426950408889634f)  // 1/sqrt(dk)*log2e

// ===========================================================================
// FAST PATH
// ===========================================================================

// prep: uniform 64x64 fp32->bf16 LDS transposes (validated rounds 11-14).
__global__ __launch_bounds__(256) void prep(
    const float* __restrict__ X,
    const float* __restrict__ Wq, const float* __restrict__ Wk,
    const float* __restrict__ Wv, const float* __restrict__ Wo,
    u16* __restrict__ Xb16, u16* __restrict__ Wall, u16* __restrict__ WoT)
{
    __shared__ u16 T[64 * 72];
    const int bid = blockIdx.x;
    const int t = threadIdx.x;
    const int tr = t >> 4;
    const int tc4 = (t & 15) * 4;

    const float* src; u16* dst;
    int src_row0, src_col0, src_pitch, dst_row0, dst_col0, dst_pitch;
    float scale = 1.0f;

    if (bid < 1024) {
        const int b = bid >> 9, rem = bid & 511;
        const int st = rem >> 3, ct = rem & 7;
        src = X + (size_t)b * CH * SEQ;
        src_row0 = ct * 64; src_col0 = st * 64; src_pitch = SEQ;
        dst = Xb16 + (size_t)b * SEQ * CH;
        dst_row0 = st * 64; dst_col0 = ct * 64; dst_pitch = CH;
    } else if (bid < 1152) {
        const int r = bid - 1024;
        const int nt = r >> 3, ct = r & 7;
        if (nt < 4)      { src = Wq; src_col0 = nt * 64;       src_pitch = KDIM; scale = QSCALE; }
        else if (nt < 8) { src = Wk; src_col0 = (nt - 4) * 64; src_pitch = KDIM; }
        else             { src = Wv; src_col0 = (nt - 8) * 64; src_pitch = VDIM; }
        src_row0 = ct * 64;
        dst = Wall; dst_row0 = nt * 64; dst_col0 = ct * 64; dst_pitch = 512;
    } else {
        const int r = bid - 1152;
        const int kt = r >> 3, nt = r & 7;
        src = Wo; src_row0 = kt * 64; src_col0 = nt * 64; src_pitch = 512;
        dst = WoT; dst_row0 = nt * 64; dst_col0 = kt * 64; dst_pitch = 512;
    }

#pragma unroll
    for (int j = 0; j < 4; ++j) {
        const int row = j * 16 + tr;
        const float4 v = *reinterpret_cast<const float4*>(
            &src[(size_t)(src_row0 + row) * src_pitch + src_col0 + tc4]);
        T[(tc4 + 0) * 72 + row] = f2bf(v.x * scale);
        T[(tc4 + 1) * 72 + row] = f2bf(v.y * scale);
        T[(tc4 + 2) * 72 + row] = f2bf(v.z * scale);
        T[(tc4 + 3) * 72 + row] = f2bf(v.w * scale);
    }
    __syncthreads();
#pragma unroll
    for (int j = 0; j < 4; ++j) {
        const int orow = j * 16 + tr;
        const ushort4 o = *reinterpret_cast<ushort4*>(&T[orow * 72 + tc4]);
        *reinterpret_cast<ushort4*>(
            &dst[(size_t)(dst_row0 + orow) * dst_pitch + dst_col0 + tc4]) = o;
    }
}

// ---------------------------------------------------------------------------
// qkv3: 128x128-tile GEMM over concatenated N=1024 (Q|K|V). Round-14 form
// (no waves_per_eu attribute — round 15 showed it neutral here).
// ---------------------------------------------------------------------------
__global__ __launch_bounds__(256, 2) void qkv3(
    const u16* __restrict__ Xb16, const u16* __restrict__ Wall,
    u16* __restrict__ Qh, u16* __restrict__ Kh, u16* __restrict__ Vh)
{
    __shared__ __align__(16) u16 As[2][128 * 40];
    __shared__ __align__(16) u16 Bs[2][128 * 40];
    const int tid = threadIdx.x;
    const int wv = tid >> 6, lane = tid & 63;
    const int c = lane & 15, quad = lane >> 4;
    const int wm = wv & 1, wn = wv >> 1;
    const int m0 = blockIdx.x * 128;
    const int ny = blockIdx.y;           // 0..7 over concat N
    const int n0 = ny * 128;

    u16* Y; int N, nbase;
    if (ny < 2)      { Y = Qh; N = KDIM; nbase = 0; }
    else if (ny < 4) { Y = Kh; N = KDIM; nbase = 256; }
    else             { Y = Vh; N = VDIM; nbase = 512; }

    const int srow = tid >> 1, scol = (tid & 1) * 16;  // staging: row, 16-col

    f32x4 acc[4][4];
#pragma unroll
    for (int i = 0; i < 4; ++i)
#pragma unroll
        for (int g = 0; g < 4; ++g) acc[i][g] = (f32x4){0.f, 0.f, 0.f, 0.f};

    uint4 ar0, ar1, br0, br1;
    auto ld = [&](int k0) {
        const uint4* ap = reinterpret_cast<const uint4*>(
            &Xb16[(size_t)(m0 + srow) * 512 + k0 + scol]);
        ar0 = ap[0]; ar1 = ap[1];
        const uint4* bp = reinterpret_cast<const uint4*>(
            &Wall[(size_t)(n0 + srow) * 512 + k0 + scol]);
        br0 = bp[0]; br1 = bp[1];
    };
    auto stage = [&](int buf) {
        uint4* ad = reinterpret_cast<uint4*>(&As[buf][srow * 40 + scol]);
        ad[0] = ar0; ad[1] = ar1;
        uint4* bd = reinterpret_cast<uint4*>(&Bs[buf][srow * 40 + scol]);
        bd[0] = br0; bd[1] = br1;
    };

    ld(0);
    stage(0);
    ld(32);

    for (int i = 0; i < 16; ++i) {
        const int cur = i & 1;
        __syncthreads();
        stage(cur ^ 1);
        const int k0n = (i + 2 < 16) ? (i + 2) * 32 : 15 * 32;
        ld(k0n);
        bf16x8 af[4], bf_[4];
#pragma unroll
        for (int j = 0; j < 4; ++j) {
            af[j] = *reinterpret_cast<bf16x8*>(
                &As[cur][(wm * 64 + 16 * j + c) * 40 + quad * 8]);
            bf_[j] = *reinterpret_cast<bf16x8*>(
                &Bs[cur][(wn * 64 + 16 * j + c) * 40 + quad * 8]);
        }
#pragma unroll
        for (int j = 0; j < 4; ++j)
#pragma unroll
            for (int g = 0; g < 4; ++g)
                acc[j][g] = __builtin_amdgcn_mfma_f32_16x16x32_bf16(
                    af[j], bf_[g], acc[j][g], 0, 0, 0);
    }
#pragma unroll
    for (int j = 0; j < 4; ++j)
#pragma unroll
        for (int r = 0; r < 4; ++r) {
            const int row = m0 + wm * 64 + 16 * j + quad * 4 + r;
            const int col = n0 - nbase + wn * 64 + c;
#pragma unroll
            for (int g = 0; g < 4; ++g)
                Y[(size_t)row * N + col + 16 * g] = f2bf(acc[j][g][r]);
        }
}

// ---------------------------------------------------------------------------
// oproj3: 128x128-tile GEMM, round-14 form.
// ---------------------------------------------------------------------------
__global__ __launch_bounds__(256, 2) void oproj3(
    const u16* __restrict__ A, const u16* __restrict__ WoT,
    float* __restrict__ Out)
{
    __shared__ __align__(16) u16 As[2][128 * 40];
    __shared__ __align__(16) u16 Bs[2][128 * 40];
    const int tid = threadIdx.x;
    const int wv = tid >> 6, lane = tid & 63;
    const int c = lane & 15, quad = lane >> 4;
    const int wm = wv & 1, wn = wv >> 1;
    const int m0 = blockIdx.x * 128;
    const int n0 = blockIdx.y * 128;

    const int srow = tid >> 1, scol = (tid & 1) * 16;

    f32x4 acc[4][4];
#pragma unroll
    for (int i = 0; i < 4; ++i)
#pragma unroll
        for (int g = 0; g < 4; ++g) acc[i][g] = (f32x4){0.f, 0.f, 0.f, 0.f};

    uint4 ar0, ar1, br0, br1;
    auto ld = [&](int k0) {
        const uint4* ap = reinterpret_cast<const uint4*>(
            &A[(size_t)(m0 + srow) * 512 + k0 + scol]);
        ar0 = ap[0]; ar1 = ap[1];
        const uint4* bp = reinterpret_cast<const uint4*>(
            &WoT[(size_t)(n0 + srow) * 512 + k0 + scol]);
        br0 = bp[0]; br1 = bp[1];
    };
    auto stage = [&](int buf) {
        uint4* ad = reinterpret_cast<uint4*>(&As[buf][srow * 40 + scol]);
        ad[0] = ar0; ad[1] = ar1;
        uint4* bd = reinterpret_cast<uint4*>(&Bs[buf][srow * 40 + scol]);
        bd[0] = br0; bd[1] = br1;
    };

    ld(0);
    stage(0);
    ld(32);

    for (int i = 0; i < 16; ++i) {
        const int cur = i & 1;
        __syncthreads();
        stage(cur ^ 1);
        const int k0n = (i + 2 < 16) ? (i + 2) * 32 : 15 * 32;
        ld(k0n);
        bf16x8 af[4], bf_[4];
#pragma unroll
        for (int j = 0; j < 4; ++j) {
            af[j] = *reinterpret_cast<bf16x8*>(
                &As[cur][(wm * 64 + 16 * j + c) * 40 + quad * 8]);
            bf_[j] = *reinterpret_cast<bf16x8*>(
                &Bs[cur][(wn * 64 + 16 * j + c) * 40 + quad * 8]);
        }
#pragma unroll
        for (int j = 0; j < 4; ++j)
#pragma unroll
            for (int g = 0; g < 4; ++g)
                acc[j][g] = __builtin_amdgcn_mfma_f32_16x16x32_bf16(
                    af[j], bf_[g], acc[j][g], 0, 0, 0);
    }
#pragma unroll
    for (int j = 0; j < 4; ++j)
#pragma unroll
        for (int r = 0; r < 4; ++r) {
            const int row = m0 + wm * 64 + 16 * j + quad * 4 + r;
            const int col = n0 + wn * 64 + c;
#pragma unroll
            for (int g = 0; g < 4; ++g)
                Out[(size_t)row * 512 + col + 16 * g] = acc[j][g][r];
        }
}

// ===========================================================================
// flash v10 = v7 sequential skeleton (the 4x-validated 91 us config) with
// MFMA row-sum: l = P * ones computed by 2 extra MFMAs against a constant
// all-ones B-frag (C-layout row sums land per-lane like the old l[r]).
// Removes the 16-shfl + 32-add softmax reduction and the p[4][4]/rs temps.
// exp2(-1e30) = 0 so masked lanes contribute nothing to l.
// ===========================================================================
__global__ __launch_bounds__(512, 4) void flash_mfma(
    const u16* __restrict__ Q, const u16* __restrict__ K,
    const u16* __restrict__ V, u16* __restrict__ AO)
{
    __shared__ __align__(16) union {
        struct {
            u16 Kl[2][2][64 * 40];
            u16 Vt[2][2][64 * 72];
            u16 Pl[8][16 * 72];
        } t;
        float mg[4][64][40];
    } sh;

    const int tid  = threadIdx.x;
    const int w    = tid >> 6;
    const int ws   = w & 3;
    const int wg   = w >> 2;
    const int lane = tid & 63;
    const int c    = lane & 15;
    const int quad = lane >> 4;
    const int h = blockIdx.y, b = blockIdx.z;

    const int qbA = blockIdx.x;
    const int qbB = 63 - qbA;
    const int q0A = qbA * 64, q0B = qbB * 64;

    const u16* Qb = Q + (size_t)b * SEQ * KDIM + h * DK;
    const u16* Kb = K + (size_t)b * SEQ * KDIM + h * DK;
    const u16* Vb = V + (size_t)b * SEQ * VDIM + h * DV;
    u16* AOb = AO + (size_t)b * SEQ * VDIM + h * DV;

    const bf16x8 qfA = *reinterpret_cast<const bf16x8*>(
        &Qb[(size_t)(q0A + ws * 16 + c) * KDIM + quad * 8]);
    const bf16x8 qfB = *reinterpret_cast<const bf16x8*>(
        &Qb[(size_t)(q0B + ws * 16 + c) * KDIM + quad * 8]);

    // constant all-ones B-frag: bf16 1.0 = 0x3F80 in every element
    const bf16x8 ones = {(short)0x3F80, (short)0x3F80, (short)0x3F80, (short)0x3F80,
                         (short)0x3F80, (short)0x3F80, (short)0x3F80, (short)0x3F80};

    f32x4 oA[4], oB[4];
#pragma unroll
    for (int g = 0; g < 4; ++g) {
        oA[g] = (f32x4){0.f, 0.f, 0.f, 0.f};
        oB[g] = (f32x4){0.f, 0.f, 0.f, 0.f};
    }
    f32x4 laccA = {0.f, 0.f, 0.f, 0.f}, laccB = {0.f, 0.f, 0.f, 0.f};

    const int t256 = tid & 255;
    const int krow = t256 >> 2, kc8 = (t256 & 3) * 8;
    const int vs0 = (t256 & 31) * 2, vd0 = (t256 >> 5) * 8;

    u16* const Plw = sh.t.Pl[w];
    const int T = (qbB >> 1) + 1;

    uint4 kreg, vra, vrb;
    auto ldtile = [&](int kb) {
        const int k0 = kb * 64;
        kreg = *reinterpret_cast<const uint4*>(&Kb[(size_t)(k0 + krow) * KDIM + kc8]);
        vra  = *reinterpret_cast<const uint4*>(&Vb[(size_t)(k0 + vs0) * VDIM + vd0]);
        vrb  = *reinterpret_cast<const uint4*>(&Vb[(size_t)(k0 + vs0 + 1) * VDIM + vd0]);
    };
    auto stagetile = [&](int buf) {
        *reinterpret_cast<uint4*>(&sh.t.Kl[wg][buf][krow * 40 + kc8]) = kreg;
        union { uint4 q; u16 s[8]; } ra, rb;
        ra.q = vra; rb.q = vrb;
#pragma unroll
        for (int i = 0; i < 8; ++i) {
            u32 packed = (u32)ra.s[i] | ((u32)rb.s[i] << 16);
            *reinterpret_cast<u32*>(&sh.t.Vt[wg][buf][(vd0 + i) * 72 + vs0]) = packed;
        }
    };

    ldtile(wg);
    stagetile(0);
    ldtile(2 + wg);

    for (int it = 0; it < T; ++it) {
        const int kb = 2 * it + wg;
        const int k0 = kb * 64;
        const int cur = it & 1;
        __syncthreads();
        stagetile(cur ^ 1);
        {
            int kbn = 2 * (it + 2) + wg; if (kbn > 63) kbn = 63;
            ldtile(kbn);
        }
        const u16* Klc = sh.t.Kl[wg][cur];
        const u16* Vtc = sh.t.Vt[wg][cur];

        auto compute = [&](const bf16x8& qf, int q0, bool diag,
                           f32x4* o, f32x4& lacc) {
            f32x4 s[4];
#pragma unroll
            for (int g = 0; g < 4; ++g) {
                const bf16x8 kf = *reinterpret_cast<const bf16x8*>(
                    &Klc[(c + 16 * g) * 40 + quad * 8]);
                const f32x4 z = {0.f, 0.f, 0.f, 0.f};
                s[g] = __builtin_amdgcn_mfma_f32_16x16x32_bf16(qf, kf, z, 0, 0, 0);
            }
            if (diag) {
#pragma unroll
                for (int g = 0; g < 4; ++g) {
                    const int kcol = k0 + c + 16 * g;
#pragma unroll
                    for (int r = 0; r < 4; ++r) {
                        const int qr = q0 + ws * 16 + quad * 4 + r;
                        if (kcol > qr) s[g][r] = -1e30f;
                    }
                }
            }
            // exp2 -> bf16 -> per-wave LDS strip (C-layout -> A-layout)
#pragma unroll
            for (int g = 0; g < 4; ++g)
#pragma unroll
                for (int r = 0; r < 4; ++r)
                    Plw[(quad * 4 + r) * 72 + c + 16 * g] =
                        f2bf_fast(__builtin_amdgcn_exp2f(s[g][r]));
            const bf16x8 pa0 = *reinterpret_cast<bf16x8*>(&Plw[c * 72 + quad * 8]);
            const bf16x8 pa1 = *reinterpret_cast<bf16x8*>(&Plw[c * 72 + 32 + quad * 8]);
            // l += P * ones  (row sums via matrix pipe, no shuffles)
            lacc = __builtin_amdgcn_mfma_f32_16x16x32_bf16(pa0, ones, lacc, 0, 0, 0);
            lacc = __builtin_amdgcn_mfma_f32_16x16x32_bf16(pa1, ones, lacc, 0, 0, 0);
#pragma unroll
            for (int g = 0; g < 4; ++g) {
                const bf16x8 v0 = *reinterpret_cast<const bf16x8*>(
                    &Vtc[(c + 16 * g) * 72 + quad * 8]);
                const bf16x8 v1 = *reinterpret_cast<const bf16x8*>(
                    &Vtc[(c + 16 * g) * 72 + 32 + quad * 8]);
                o[g] = __builtin_amdgcn_mfma_f32_16x16x32_bf16(pa0, v0, o[g], 0, 0, 0);
                o[g] = __builtin_amdgcn_mfma_f32_16x16x32_bf16(pa1, v1, o[g], 0, 0, 0);
            }
        };

        if (kb <= qbA) compute(qfA, q0A, kb == qbA, oA, laccA);
        if (kb <= qbB) compute(qfB, q0B, kb == qbB, oB, laccB);
    }

    __syncthreads();
    if (wg == 1) {
        float* m = sh.mg[ws][lane];
#pragma unroll
        for (int g = 0; g < 4; ++g)
#pragma unroll
            for (int r = 0; r < 4; ++r) {
                m[g * 4 + r]      = oA[g][r];
                m[16 + g * 4 + r] = oB[g][r];
            }
#pragma unroll
        for (int r = 0; r < 4; ++r) { m[32 + r] = laccA[r]; m[36 + r] = laccB[r]; }
    }
    __syncthreads();
    if (wg == 0) {
        const float* m = sh.mg[ws][lane];
#pragma unroll
        for (int g = 0; g < 4; ++g)
#pragma unroll
            for (int r = 0; r < 4; ++r) {
                oA[g][r] += m[g * 4 + r];
                oB[g][r] += m[16 + g * 4 + r];
            }
#pragma unroll
        for (int r = 0; r < 4; ++r) { laccA[r] += m[32 + r]; laccB[r] += m[36 + r]; }
#pragma unroll
        for (int r = 0; r < 4; ++r) {
            const float invA = 1.f / laccA[r];
            const float invB = 1.f / laccB[r];
            const int rowA = q0A + ws * 16 + quad * 4 + r;
            const int rowB = q0B + ws * 16 + quad * 4 + r;
#pragma unroll
            for (int g = 0; g < 4; ++g) {
                AOb[(size_t)rowA * VDIM + c + 16 * g] = f2bf(oA[g][r] * invA);
                AOb[(size_t)rowB * VDIM + c + 16 * g] = f2bf(oB[g][r] * invB);
            }
        }
    }
}

// ===========================================================================
// FALLBACK PATH (ws too small): round-10 projection kernels
// ===========================================================================
__global__ __launch_bounds__(256) void qkv_proj(
    const float* __restrict__ X,
    const float* __restrict__ Wq, const float* __restrict__ Wk,
    const float* __restrict__ Wv,
    u16* __restrict__ Qh, u16* __restrict__ Kh, u16* __restrict__ Vh)
{
    __shared__ __align__(16) u16 Xs[2][64 * 40];
    __shared__ __align__(16) u16 Wsm[2][64 * 40];
    const int tid = threadIdx.x;
    const int w = tid >> 6, lane = tid & 63;
    const int c = lane & 15, quad = lane >> 4;
    const int s0 = blockIdx.x * 64, b = blockIdx.z;
    const int ny = blockIdx.y;

    const float* Wt; u16* Y; int N, n0; float scale;
    if (ny < 4)       { Wt = Wq; Y = Qh; N = KDIM; n0 = ny * 64;       scale = QSCALE; }
    else if (ny < 8)  { Wt = Wk; Y = Kh; N = KDIM; n0 = (ny - 4) * 64; scale = 1.0f; }
    else              { Wt = Wv; Y = Vh; N = VDIM; n0 = (ny - 8) * 64; scale = 1.0f; }

    const float* Xb = X + (size_t)b * CH * SEQ;
    const int cp = tid >> 4;
    const int s4 = (tid & 15) * 4;

    f32x4 acc[4];
#pragma unroll
    for (int g = 0; g < 4; ++g) acc[g] = (f32x4){0.f, 0.f, 0.f, 0.f};

    auto ldx = [&](int c0, float4& a, float4& bb) {
        a  = *reinterpret_cast<const float4*>(&Xb[(size_t)(c0 + 2 * cp) * SEQ + s0 + s4]);
        bb = *reinterpret_cast<const float4*>(&Xb[(size_t)(c0 + 2 * cp + 1) * SEQ + s0 + s4]);
    };
    auto ldwf = [&](int c0, float4& a, float4& bb) {
        a  = *reinterpret_cast<const float4*>(&Wt[(size_t)(c0 + 2 * cp) * N + n0 + s4]);
        bb = *reinterpret_cast<const float4*>(&Wt[(size_t)(c0 + 2 * cp + 1) * N + n0 + s4]);
    };
    auto stage = [&](int buf, const float4& xa, const float4& xb,
                     const float4& wa, const float4& wb) {
        const float a[4] = {xa.x, xa.y, xa.z, xa.w};
        const float bb[4] = {xb.x, xb.y, xb.z, xb.w};
        const float aw[4] = {wa.x, wa.y, wa.z, wa.w};
        const float bw[4] = {wb.x, wb.y, wb.z, wb.w};
#pragma unroll
        for (int i = 0; i < 4; ++i) {
            *reinterpret_cast<u32*>(&Xs[buf][(s4 + i) * 40 + 2 * cp]) = pack2f(a[i], bb[i]);
            *reinterpret_cast<u32*>(&Wsm[buf][(s4 + i) * 40 + 2 * cp]) = pack2f(aw[i], bw[i]);
        }
    };

    float4 xa, xb, wa, wb;
    ldx(0, xa, xb); ldwf(0, wa, wb);
    stage(0, xa, xb, wa, wb);
    ldx(32, xa, xb); ldwf(32, wa, wb);

    for (int i = 0; i < 16; ++i) {
        const int cur = i & 1;
        __syncthreads();
        stage(cur ^ 1, xa, xb, wa, wb);
        const int c0n = (i + 2 < 16) ? (i + 2) * 32 : 15 * 32;
        ldx(c0n, xa, xb); ldwf(c0n, wa, wb);
        const bf16x8 af = *reinterpret_cast<bf16x8*>(&Xs[cur][(w * 16 + c) * 40 + quad * 8]);
#pragma unroll
        for (int g = 0; g < 4; ++g) {
            bf16x8 bf_ = *reinterpret_cast<bf16x8*>(&Wsm[cur][(c + 16 * g) * 40 + quad * 8]);
            acc[g] = __builtin_amdgcn_mfma_f32_16x16x32_bf16(af, bf_, acc[g], 0, 0, 0);
        }
    }
    u16* Yb = Y + (size_t)b * SEQ * N;
#pragma unroll
    for (int r = 0; r < 4; ++r) {
        const int row = s0 + w * 16 + quad * 4 + r;
#pragma unroll
        for (int g = 0; g < 4; ++g)
            Yb[(size_t)row * N + n0 + c + 16 * g] = f2bf(acc[g][r] * scale);
    }
}

__global__ __launch_bounds__(256) void oproj_mfma(
    const u16* __restrict__ A, const float* __restrict__ Wo,
    float* __restrict__ Out)
{
    __shared__ __align__(16) u16 Ws[2][64 * 40];
    const int tid = threadIdx.x;
    const int w = tid >> 6, lane = tid & 63;
    const int c = lane & 15, quad = lane >> 4;
    const int m0 = blockIdx.x * 64, n0 = blockIdx.y * 64;
    const int kp = tid >> 4;
    const int n4 = (tid & 15) * 4;
    const u16* Arow = &A[(size_t)(m0 + w * 16 + c) * 512];

    f32x4 acc[4];
#pragma unroll
    for (int g = 0; g < 4; ++g) acc[g] = (f32x4){0.f, 0.f, 0.f, 0.f};

    auto ldwf = [&](int k0, float4& a, float4& bb) {
        a  = *reinterpret_cast<const float4*>(&Wo[(size_t)(k0 + 2 * kp) * 512 + n0 + n4]);
        bb = *reinterpret_cast<const float4*>(&Wo[(size_t)(k0 + 2 * kp + 1) * 512 + n0 + n4]);
    };
    auto stage = [&](int buf, const float4& wa, const float4& wb) {
        const float a[4] = {wa.x, wa.y, wa.z, wa.w};
        const float bb[4] = {wb.x, wb.y, wb.z, wb.w};
#pragma unroll
        for (int i = 0; i < 4; ++i)
            *reinterpret_cast<u32*>(&Ws[buf][(n4 + i) * 40 + 2 * kp]) = pack2f(a[i], bb[i]);
    };

    float4 wa, wb;
    ldwf(0, wa, wb);
    stage(0, wa, wb);
    ldwf(32, wa, wb);
    bf16x8 afc = *reinterpret_cast<const bf16x8*>(&Arow[quad * 8]);

    for (int i = 0; i < 16; ++i) {
        const int cur = i & 1;
        __syncthreads();
        stage(cur ^ 1, wa, wb);
        const int k0n = (i + 2 < 16) ? (i + 2) * 32 : 15 * 32;
        ldwf(k0n, wa, wb);
        const int k0a = (i + 1 < 16) ? (i + 1) * 32 : 15 * 32;
        const bf16x8 afn = *reinterpret_cast<const bf16x8*>(&Arow[k0a + quad * 8]);
#pragma unroll
        for (int g = 0; g < 4; ++g) {
            bf16x8 bf_ = *reinterpret_cast<bf16x8*>(&Ws[cur][(c + 16 * g) * 40 + quad * 8]);
            acc[g] = __builtin_amdgcn_mfma_f32_16x16x32_bf16(afc, bf_, acc[g], 0, 0, 0);
        }
        afc = afn;
    }
#pragma unroll
    for (int r = 0; r < 4; ++r) {
        const int row = m0 + w * 16 + quad * 4 + r;
#pragma unroll
        for (int g = 0; g < 4; ++g)
            Out[(size_t)row * 512 + n0 + c + 16 * g] = acc[g][r];
    }
}

extern "C" void kernel_launch(void* const* d_in, const int* in_sizes, int n_in,
                              void* d_out, int out_size, void* d_ws, size_t ws_size,
                              hipStream_t stream) {
    const float* X  = (const float*)d_in[0];
    const float* Wq = (const float*)d_in[1];
    const float* Wk = (const float*)d_in[2];
    const float* Wv = (const float*)d_in[3];
    const float* Wo = (const float*)d_in[4];
    float* out = (float*)d_out;

    const size_t qk = (size_t)BATCH * SEQ * KDIM;
    const size_t vs = (size_t)BATCH * SEQ * VDIM;
    u16* Qh  = (u16*)d_ws;        // 4 MB
    u16* Kh  = Qh + qk;           // 4 MB
    u16* Vh  = Kh + qk;           // 8 MB
    u16* XA  = Vh + vs;           // 8 MB: Xb16 during qkv, AOh after flash
    u16* Wall = XA + vs;          // 1 MB
    u16* WoT  = Wall + 1024 * 512;// 0.5 MB
    const size_t need_fast = (size_t)(WoT + 512 * 512 - (u16*)d_ws) * sizeof(u16);

    if (ws_size >= need_fast) {
        prep<<<dim3(1216), 256, 0, stream>>>(X, Wq, Wk, Wv, Wo, XA, Wall, WoT);
        qkv3<<<dim3((BATCH * SEQ) / 128, 8), 256, 0, stream>>>(XA, Wall, Qh, Kh, Vh);
        flash_mfma<<<dim3(32, NHEADS, BATCH), 512, 0, stream>>>(Qh, Kh, Vh, XA);
        oproj3<<<dim3((BATCH * SEQ) / 128, 4), 256, 0, stream>>>(XA, WoT, out);
    } else {
        u16* AOh = XA;
        qkv_proj<<<dim3(SEQ / 64, 16, BATCH), 256, 0, stream>>>(
            X, Wq, Wk, Wv, Qh, Kh, Vh);
        flash_mfma<<<dim3(32, NHEADS, BATCH), 512, 0, stream>>>(Qh, Kh, Vh, AOh);
        oproj_mfma<<<dim3((BATCH * SEQ) / 64, VDIM / 64), 256, 0, stream>>>(AOh, Wo, out);
    }
}